// Round 1
// baseline (220.351 us; speedup 1.0000x reference)
//
#include <hip/hip_runtime.h>
#include <math.h>

#define S 256
#define NPIX (S * S)          // 65536
#define B 64
#define NQUAD 16

// ---------------------------------------------------------------------------
// Fused kernel: each block (a) redundantly solves the per-batch pose in its
// prologue (bit-identical across the 64 blocks of a batch — no inter-block
// communication needed), then (b) applies the affine transform to its 1024
// contiguous pixels. Bulk float4 loads are issued BEFORE the solve phases so
// HBM streaming overlaps the solve's latency chain.
// Grid: B*NPIX/4/256 = 4096 blocks x 256 threads, 4 pixels per thread.
// ---------------------------------------------------------------------------
__global__ __launch_bounds__(256) void fused_pose_apply(
    const float* __restrict__ Offset,      // [B][3][NPIX]
    const float* __restrict__ Posmap,      // [B][3][NPIX]
    const float* __restrict__ meanp,       // [3][NPIX]
    const int*   __restrict__ uv,          // [68][2]
    float*       __restrict__ out)         // [B][3][NPIX]
{
    const int tid = blockIdx.x * 256 + threadIdx.x;   // B * NPIX/4 threads
    const int b   = tid >> 14;                        // same for whole block
    const int n   = (tid & 16383) << 2;               // pixel base
    const int t   = threadIdx.x;

    __shared__ double sp[64][3];           // kpt_src (offsetmap at kpt)
    __shared__ double sq[64][3];           // kpt_dst (posmap at kpt)
    __shared__ double sR[NQUAD][9];
    __shared__ double sT[NQUAD][3];
    __shared__ int    scol[64];
    __shared__ float  sprm[12];            // {R_p row-major, T_p}

    const float* offb = Offset + (size_t)b * 3 * NPIX;

    // ---- issue bulk streaming loads early (complete while block solves) ----
    const float4 o0 = *(const float4*)(offb + 0 * NPIX + n);
    const float4 o1 = *(const float4*)(offb + 1 * NPIX + n);
    const float4 o2 = *(const float4*)(offb + 2 * NPIX + n);
    const float4 m0 = *(const float4*)(meanp + 0 * NPIX + n);
    const float4 m1 = *(const float4*)(meanp + 1 * NPIX + n);
    const float4 m2 = *(const float4*)(meanp + 2 * NPIX + n);

    // ---- gather keypoints (threads 0..63, one kpt each) ----
    if (t < 64) {
        const int u = uv[2 * t + 0];
        const int v = uv[2 * t + 1];
        scol[t] = v;
        const int kn = u * S + v;
        const float* posb = Posmap + (size_t)b * 3 * NPIX;
#pragma unroll
        for (int c = 0; c < 3; ++c) {
            sp[t][c] = (double)offb[c * NPIX + kn] * 6.0 + (double)meanp[c * NPIX + kn];
            sq[t][c] = (double)posb[c * NPIX + kn];
        }
    }
    __syncthreads();

    // ---- per-quad 3x3 solve: R = inv(A) @ Bm, T = mean(q - p@R) ----
    if (t < NQUAD) {
        const int k0 = 4 * t;
        double A[3][3], Bm[3][3];
#pragma unroll
        for (int r = 0; r < 3; ++r)
#pragma unroll
            for (int c = 0; c < 3; ++c) {
                A[r][c]  = sp[k0][c] - sp[k0 + 1 + r][c];
                Bm[r][c] = sq[k0][c] - sq[k0 + 1 + r][c];
            }
        const double c00 = A[1][1] * A[2][2] - A[1][2] * A[2][1];
        const double c01 = A[1][2] * A[2][0] - A[1][0] * A[2][2];
        const double c02 = A[1][0] * A[2][1] - A[1][1] * A[2][0];
        const double det = A[0][0] * c00 + A[0][1] * c01 + A[0][2] * c02;
        const double id  = 1.0 / det;
        double inv[3][3];
        inv[0][0] = c00 * id;
        inv[0][1] = (A[0][2] * A[2][1] - A[0][1] * A[2][2]) * id;
        inv[0][2] = (A[0][1] * A[1][2] - A[0][2] * A[1][1]) * id;
        inv[1][0] = c01 * id;
        inv[1][1] = (A[0][0] * A[2][2] - A[0][2] * A[2][0]) * id;
        inv[1][2] = (A[0][2] * A[1][0] - A[0][0] * A[1][2]) * id;
        inv[2][0] = c02 * id;
        inv[2][1] = (A[0][1] * A[2][0] - A[0][0] * A[2][1]) * id;
        inv[2][2] = (A[0][0] * A[1][1] - A[0][1] * A[1][0]) * id;

        double R[3][3];
#pragma unroll
        for (int i = 0; i < 3; ++i)
#pragma unroll
            for (int j = 0; j < 3; ++j) {
                R[i][j] = inv[i][0] * Bm[0][j] + inv[i][1] * Bm[1][j] + inv[i][2] * Bm[2][j];
                sR[t][i * 3 + j] = R[i][j];
            }
#pragma unroll
        for (int c = 0; c < 3; ++c) {
            double acc = 0.0;
#pragma unroll
            for (int j = 0; j < 4; ++j) {
                const double pr = sp[k0 + j][0] * R[0][c] +
                                  sp[k0 + j][1] * R[1][c] +
                                  sp[k0 + j][2] * R[2][c];
                acc += sq[k0 + j][c] - pr;
            }
            sT[t][c] = acc * 0.25;
        }
    }
    __syncthreads();

    // ---- finalize (cheap; single thread) ----
    if (t == 0) {
        double r00 = 0.0, r10 = 0.0, r20 = 0.0;
        for (int q = 0; q < NQUAD; ++q) {
            r00 += sR[q][0];
            r10 += sR[q][3];
            r20 += sR[q][6];
        }
        r00 /= NQUAD; r10 /= NQUAD; r20 /= NQUAD;
        const double yaw = atan2(-r20, sqrt(r00 * r00 + r10 * r10));
        const double yr  = yaw / M_PI;
        const double left  = fmax(yr * (double)S, 0.0);
        const double right = fmin((double)S + yr * (double)S, (double)S);

        double w[NQUAD];
        double s = 0.0;
        for (int q = 0; q < NQUAD; ++q) {
            double wq = 1.0;
#pragma unroll
            for (int j = 0; j < 4; ++j) {
                const double col = (double)scol[4 * q + j];
                const double vis = (col <= left || col >= right) ? 0.001 : 1.0;
                wq *= vis;
            }
            w[q] = wq;
            s += wq;
        }
        double Rp[9] = {0, 0, 0, 0, 0, 0, 0, 0, 0};
        double Tp[3] = {0, 0, 0};
        for (int q = 0; q < NQUAD; ++q) {
#pragma unroll
            for (int e = 0; e < 9; ++e) Rp[e] += w[q] * sR[q][e];
#pragma unroll
            for (int e = 0; e < 3; ++e) Tp[e] += w[q] * sT[q][e];
        }
        const double sinv = 1.0 / s;
#pragma unroll
        for (int e = 0; e < 9; ++e) sprm[e] = (float)(Rp[e] * sinv);
#pragma unroll
        for (int e = 0; e < 3; ++e) sprm[9 + e] = (float)(Tp[e] * sinv);
    }
    __syncthreads();

    // ---- bulk affine apply ----
    const float r00 = sprm[0], r01 = sprm[1], r02 = sprm[2];
    const float r10 = sprm[3], r11 = sprm[4], r12 = sprm[5];
    const float r20 = sprm[6], r21 = sprm[7], r22 = sprm[8];
    const float t0 = sprm[9], t1 = sprm[10], t2 = sprm[11];

    float4 x, y, z;
    x.x = fmaf(o0.x, 6.f, m0.x); x.y = fmaf(o0.y, 6.f, m0.y);
    x.z = fmaf(o0.z, 6.f, m0.z); x.w = fmaf(o0.w, 6.f, m0.w);
    y.x = fmaf(o1.x, 6.f, m1.x); y.y = fmaf(o1.y, 6.f, m1.y);
    y.z = fmaf(o1.z, 6.f, m1.z); y.w = fmaf(o1.w, 6.f, m1.w);
    z.x = fmaf(o2.x, 6.f, m2.x); z.y = fmaf(o2.y, 6.f, m2.y);
    z.z = fmaf(o2.z, 6.f, m2.z); z.w = fmaf(o2.w, 6.f, m2.w);

    float4 u, v, wv;
    u.x = fmaf(x.x, r00, fmaf(y.x, r10, fmaf(z.x, r20, t0)));
    u.y = fmaf(x.y, r00, fmaf(y.y, r10, fmaf(z.y, r20, t0)));
    u.z = fmaf(x.z, r00, fmaf(y.z, r10, fmaf(z.z, r20, t0)));
    u.w = fmaf(x.w, r00, fmaf(y.w, r10, fmaf(z.w, r20, t0)));
    v.x = fmaf(x.x, r01, fmaf(y.x, r11, fmaf(z.x, r21, t1)));
    v.y = fmaf(x.y, r01, fmaf(y.y, r11, fmaf(z.y, r21, t1)));
    v.z = fmaf(x.z, r01, fmaf(y.z, r11, fmaf(z.z, r21, t1)));
    v.w = fmaf(x.w, r01, fmaf(y.w, r11, fmaf(z.w, r21, t1)));
    wv.x = fmaf(x.x, r02, fmaf(y.x, r12, fmaf(z.x, r22, t2)));
    wv.y = fmaf(x.y, r02, fmaf(y.y, r12, fmaf(z.y, r22, t2)));
    wv.z = fmaf(x.z, r02, fmaf(y.z, r12, fmaf(z.z, r22, t2)));
    wv.w = fmaf(x.w, r02, fmaf(y.w, r12, fmaf(z.w, r22, t2)));

    float* outb = out + (size_t)b * 3 * NPIX;
    *(float4*)(outb + 0 * NPIX + n) = u;
    *(float4*)(outb + 1 * NPIX + n) = v;
    *(float4*)(outb + 2 * NPIX + n) = wv;
}

extern "C" void kernel_launch(void* const* d_in, const int* in_sizes, int n_in,
                              void* d_out, int out_size, void* d_ws, size_t ws_size,
                              hipStream_t stream) {
    (void)in_sizes; (void)n_in; (void)out_size; (void)d_ws; (void)ws_size;
    const float* Offset = (const float*)d_in[0];   // [64][3][256][256]
    const float* Posmap = (const float*)d_in[1];   // [64][3][256][256]
    const float* meanp  = (const float*)d_in[2];   // [3][256][256]
    const int*   uv     = (const int*)d_in[3];     // [68][2]
    float* out = (float*)d_out;

    const int threads_total = B * (NPIX / 4);      // 1,048,576
    fused_pose_apply<<<threads_total / 256, 256, 0, stream>>>(
        Offset, Posmap, meanp, uv, out);
}

// Round 2
// 132.312 us; speedup vs baseline: 1.6654x; 1.6654x over previous
//
#include <hip/hip_runtime.h>
#include <math.h>

#define S 256
#define NPIX (S * S)          // 65536
#define B 64
#define NQUAD 16

// ---------------------------------------------------------------------------
// Kernel A: per-batch pose solve in double precision.
// Grid: B blocks x 64 threads (1 wave). Writes params[b][12] = {R_p, T_p}.
// Finalize is parallelized across the 16 quad lanes via __shfl_xor butterfly
// reductions (width 16) instead of a single-thread serial loop.
// ---------------------------------------------------------------------------
__global__ __launch_bounds__(64) void pose_solve_kernel(
    const float* __restrict__ Offset,      // [B][3][S][S]
    const float* __restrict__ Posmap,      // [B][3][S][S]
    const float* __restrict__ meanp,       // [3][S][S]
    const int*   __restrict__ uv,          // [68][2]
    float*       __restrict__ params)      // [B][12]
{
    const int b = blockIdx.x;
    const int t = threadIdx.x;             // 0..63 -> keypoint index

    __shared__ double sp[64][3];           // kpt_src (offsetmap at kpt)
    __shared__ double sq[64][3];           // kpt_dst (posmap at kpt)
    __shared__ int    scol[64];

    // ---- gather keypoints (one per thread) ----
    {
        const int u = uv[2 * t + 0];
        const int v = uv[2 * t + 1];
        scol[t] = v;
        const int n = u * S + v;
        const float* offb = Offset + (size_t)b * 3 * NPIX;
        const float* posb = Posmap + (size_t)b * 3 * NPIX;
#pragma unroll
        for (int c = 0; c < 3; ++c) {
            sp[t][c] = (double)offb[c * NPIX + n] * 6.0 + (double)meanp[c * NPIX + n];
            sq[t][c] = (double)posb[c * NPIX + n];
        }
    }
    __syncthreads();

    // ---- per-quad 3x3 solve on lanes 0..15: R = inv(A) @ Bm, T = mean(q-p@R)
    double R[3][3] = {{0,0,0},{0,0,0},{0,0,0}};
    double T[3] = {0,0,0};
    if (t < NQUAD) {
        const int k0 = 4 * t;
        double A[3][3], Bm[3][3];
#pragma unroll
        for (int r = 0; r < 3; ++r)
#pragma unroll
            for (int c = 0; c < 3; ++c) {
                A[r][c]  = sp[k0][c] - sp[k0 + 1 + r][c];
                Bm[r][c] = sq[k0][c] - sq[k0 + 1 + r][c];
            }
        const double c00 = A[1][1] * A[2][2] - A[1][2] * A[2][1];
        const double c01 = A[1][2] * A[2][0] - A[1][0] * A[2][2];
        const double c02 = A[1][0] * A[2][1] - A[1][1] * A[2][0];
        const double det = A[0][0] * c00 + A[0][1] * c01 + A[0][2] * c02;
        const double id  = 1.0 / det;
        double inv[3][3];
        inv[0][0] = c00 * id;
        inv[0][1] = (A[0][2] * A[2][1] - A[0][1] * A[2][2]) * id;
        inv[0][2] = (A[0][1] * A[1][2] - A[0][2] * A[1][1]) * id;
        inv[1][0] = c01 * id;
        inv[1][1] = (A[0][0] * A[2][2] - A[0][2] * A[2][0]) * id;
        inv[1][2] = (A[0][2] * A[1][0] - A[0][0] * A[1][2]) * id;
        inv[2][0] = c02 * id;
        inv[2][1] = (A[0][1] * A[2][0] - A[0][0] * A[2][1]) * id;
        inv[2][2] = (A[0][0] * A[1][1] - A[0][1] * A[1][0]) * id;

#pragma unroll
        for (int i = 0; i < 3; ++i)
#pragma unroll
            for (int j = 0; j < 3; ++j)
                R[i][j] = inv[i][0] * Bm[0][j] + inv[i][1] * Bm[1][j] + inv[i][2] * Bm[2][j];

#pragma unroll
        for (int c = 0; c < 3; ++c) {
            double acc = 0.0;
#pragma unroll
            for (int j = 0; j < 4; ++j) {
                const double pr = sp[k0 + j][0] * R[0][c] +
                                  sp[k0 + j][1] * R[1][c] +
                                  sp[k0 + j][2] * R[2][c];
                acc += sq[k0 + j][c] - pr;
            }
            T[c] = acc * 0.25;
        }
    }

    // ---- finalize, parallel over the 16 quad lanes (width-16 butterflies) --
    // R_coarse entries needed for yaw: mean over quads of R[0][0],R[1][0],R[2][0]
    double r00 = R[0][0], r10 = R[1][0], r20 = R[2][0];
#pragma unroll
    for (int m = 1; m < 16; m <<= 1) {
        r00 += __shfl_xor(r00, m, 16);
        r10 += __shfl_xor(r10, m, 16);
        r20 += __shfl_xor(r20, m, 16);
    }
    r00 *= (1.0 / NQUAD); r10 *= (1.0 / NQUAD); r20 *= (1.0 / NQUAD);

    // yaw/left/right computed wave-wide (same latency as one lane)
    const double yaw = atan2(-r20, sqrt(r00 * r00 + r10 * r10));
    const double yr  = yaw / M_PI;
    const double left  = fmax(yr * (double)S, 0.0);
    const double right = fmin((double)S + yr * (double)S, (double)S);

    // per-quad visibility weight (lane q handles quad q)
    const int q16 = t & 15;
    double wq = 1.0;
#pragma unroll
    for (int j = 0; j < 4; ++j) {
        const double col = (double)scol[4 * q16 + j];
        const double vis = (col <= left || col >= right) ? 0.001 : 1.0;
        wq *= vis;
    }

    // weighted sums of R (9), T (3), and s (1): butterfly-reduce 13 doubles
    double acc[13];
#pragma unroll
    for (int i = 0; i < 3; ++i)
#pragma unroll
        for (int j = 0; j < 3; ++j) acc[i * 3 + j] = wq * R[i][j];
#pragma unroll
    for (int e = 0; e < 3; ++e) acc[9 + e] = wq * T[e];
    acc[12] = wq;
#pragma unroll
    for (int m = 1; m < 16; m <<= 1) {
#pragma unroll
        for (int e = 0; e < 13; ++e) acc[e] += __shfl_xor(acc[e], m, 16);
    }

    if (t == 0) {
        float* pb = params + b * 12;
        const double sinv = 1.0 / acc[12];
#pragma unroll
        for (int e = 0; e < 12; ++e) pb[e] = (float)(acc[e] * sinv);
    }
}

// ---------------------------------------------------------------------------
// Kernel B: bulk affine apply. out[b][c'][n] = sum_c x_c[n]*Rp[c][c'] + Tp[c']
// with x_c[n] = Offset[b][c][n]*6 + mean[c][n].
// Grid: B*NPIX/4/256 blocks x 256 threads, 4 pixels (float4) per thread.
// ---------------------------------------------------------------------------
__global__ __launch_bounds__(256) void apply_pose_kernel(
    const float* __restrict__ Offset,      // [B][3][NPIX]
    const float* __restrict__ meanp,       // [3][NPIX]
    const float* __restrict__ params,      // [B][12]
    float*       __restrict__ out)         // [B][3][NPIX]
{
    const int tid = blockIdx.x * 256 + threadIdx.x;   // B * NPIX/4 threads
    const int b   = tid >> 14;                        // tid / (NPIX/4)
    const int n   = (tid & 16383) << 2;               // pixel base

    const float* pb = params + b * 12;
    const float r00 = pb[0], r01 = pb[1], r02 = pb[2];
    const float r10 = pb[3], r11 = pb[4], r12 = pb[5];
    const float r20 = pb[6], r21 = pb[7], r22 = pb[8];
    const float t0 = pb[9], t1 = pb[10], t2 = pb[11];

    const float* offb = Offset + (size_t)b * 3 * NPIX;
    const float4 o0 = *(const float4*)(offb + 0 * NPIX + n);
    const float4 o1 = *(const float4*)(offb + 1 * NPIX + n);
    const float4 o2 = *(const float4*)(offb + 2 * NPIX + n);
    const float4 m0 = *(const float4*)(meanp + 0 * NPIX + n);
    const float4 m1 = *(const float4*)(meanp + 1 * NPIX + n);
    const float4 m2 = *(const float4*)(meanp + 2 * NPIX + n);

    float4 x, y, z;
    x.x = fmaf(o0.x, 6.f, m0.x); x.y = fmaf(o0.y, 6.f, m0.y);
    x.z = fmaf(o0.z, 6.f, m0.z); x.w = fmaf(o0.w, 6.f, m0.w);
    y.x = fmaf(o1.x, 6.f, m1.x); y.y = fmaf(o1.y, 6.f, m1.y);
    y.z = fmaf(o1.z, 6.f, m1.z); y.w = fmaf(o1.w, 6.f, m1.w);
    z.x = fmaf(o2.x, 6.f, m2.x); z.y = fmaf(o2.y, 6.f, m2.y);
    z.z = fmaf(o2.z, 6.f, m2.z); z.w = fmaf(o2.w, 6.f, m2.w);

    float4 u, v, wv;
    u.x = fmaf(x.x, r00, fmaf(y.x, r10, fmaf(z.x, r20, t0)));
    u.y = fmaf(x.y, r00, fmaf(y.y, r10, fmaf(z.y, r20, t0)));
    u.z = fmaf(x.z, r00, fmaf(y.z, r10, fmaf(z.z, r20, t0)));
    u.w = fmaf(x.w, r00, fmaf(y.w, r10, fmaf(z.w, r20, t0)));
    v.x = fmaf(x.x, r01, fmaf(y.x, r11, fmaf(z.x, r21, t1)));
    v.y = fmaf(x.y, r01, fmaf(y.y, r11, fmaf(z.y, r21, t1)));
    v.z = fmaf(x.z, r01, fmaf(y.z, r11, fmaf(z.z, r21, t1)));
    v.w = fmaf(x.w, r01, fmaf(y.w, r11, fmaf(z.w, r21, t1)));
    wv.x = fmaf(x.x, r02, fmaf(y.x, r12, fmaf(z.x, r22, t2)));
    wv.y = fmaf(x.y, r02, fmaf(y.y, r12, fmaf(z.y, r22, t2)));
    wv.z = fmaf(x.z, r02, fmaf(y.z, r12, fmaf(z.z, r22, t2)));
    wv.w = fmaf(x.w, r02, fmaf(y.w, r12, fmaf(z.w, r22, t2)));

    float* outb = out + (size_t)b * 3 * NPIX;
    *(float4*)(outb + 0 * NPIX + n) = u;
    *(float4*)(outb + 1 * NPIX + n) = v;
    *(float4*)(outb + 2 * NPIX + n) = wv;
}

extern "C" void kernel_launch(void* const* d_in, const int* in_sizes, int n_in,
                              void* d_out, int out_size, void* d_ws, size_t ws_size,
                              hipStream_t stream) {
    (void)in_sizes; (void)n_in; (void)out_size; (void)ws_size;
    const float* Offset = (const float*)d_in[0];   // [64][3][256][256]
    const float* Posmap = (const float*)d_in[1];   // [64][3][256][256]
    const float* meanp  = (const float*)d_in[2];   // [3][256][256]
    const int*   uv     = (const int*)d_in[3];     // [68][2]
    float* out = (float*)d_out;
    float* params = (float*)d_ws;                  // [64][12]

    pose_solve_kernel<<<B, 64, 0, stream>>>(Offset, Posmap, meanp, uv, params);

    const int threads_total = B * (NPIX / 4);      // 1,048,576
    apply_pose_kernel<<<threads_total / 256, 256, 0, stream>>>(Offset, meanp, params, out);
}